// Round 15
// baseline (1375.437 us; speedup 1.0000x reference)
//
#include <hip/hip_runtime.h>

#define NG 4096
#define NP 512
#define BSZ 128
#define NT 100

typedef _Float16 f16;
typedef __attribute__((ext_vector_type(8))) _Float16 half8;
typedef __attribute__((ext_vector_type(4))) _Float16 half4v;
typedef __attribute__((ext_vector_type(16))) float f32x16;

__device__ inline f32x16 mfma16(half8 a, half8 b, f32x16 c) {
  return __builtin_amdgcn_mfma_f32_32x32x16_f16(a, b, c, 0, 0, 0);
}
__device__ __forceinline__ void gload16(const void* g, void* l) {
  __builtin_amdgcn_global_load_lds(
      (const __attribute__((address_space(1))) void*)g,
      (__attribute__((address_space(3))) void*)l, 16, 0, 0);
}
__device__ __forceinline__ void pipe_bar8() {
  __builtin_amdgcn_sched_barrier(0);
  asm volatile("s_waitcnt vmcnt(8)" ::: "memory");
  __builtin_amdgcn_s_barrier();
  __builtin_amdgcn_sched_barrier(0);
}
__device__ __forceinline__ void pipe_bar4() {
  __builtin_amdgcn_sched_barrier(0);
  asm volatile("s_waitcnt vmcnt(4)" ::: "memory");
  __builtin_amdgcn_s_barrier();
  __builtin_amdgcn_sched_barrier(0);
}
__device__ __forceinline__ void pipe_bar0() {
  __builtin_amdgcn_sched_barrier(0);
  asm volatile("s_waitcnt vmcnt(0)" ::: "memory");
  __builtin_amdgcn_s_barrier();
  __builtin_amdgcn_sched_barrier(0);
}

// ---------------- prep: all f32 -> fp16 conversions in ONE launch ----------------
__global__ __launch_bounds__(256) void conv_all(
    const float* __restrict__ whh, const float* __restrict__ wdec,
    const float* __restrict__ wenc, const float* __restrict__ p0,
    f16* __restrict__ whh16, f16* __restrict__ wdec16,
    f16* __restrict__ wenc16, f16* __restrict__ p016)
{
  int i = blockIdx.x * 256 + threadIdx.x;
  const float* src; f16* dst; int off;
  if (i < 4194304)      { src = whh;  dst = whh16;  off = 0; }
  else if (i < 4718592) { src = wdec; dst = wdec16; off = 4194304; }
  else if (i < 5242880) { src = wenc; dst = wenc16; off = 4718592; }
  else if (i < 5259264) { src = p0;   dst = p016;   off = 5242880; }
  else return;
  const int j = i - off;
  const float4 x = ((const float4*)src)[j];
  half4v h = { (f16)x.x, (f16)x.y, (f16)x.z, (f16)x.w };
  *(half4v*)&dst[(size_t)j * 4] = h;
}

// ---------------- K-split fp16 GEMM, 3-buf counted-vmcnt pipeline (r12-verbatim) ----------------
template<int NS, int KROW>
__global__ __launch_bounds__(256, 1) void gemm_ksplit(
    const f16* __restrict__ bmat, const f16* __restrict__ amat,
    f16* __restrict__ part)
{
  constexpr int NCH = KROW / (NS * 64);
  __shared__ __align__(128) char lds[3 * 32768];
  const int tid = threadIdx.x;
  const int w = tid >> 6, lane = tid & 63;
  const int wm = w & 1, wn = w >> 1;
  const int l31 = lane & 31, hi = lane >> 5;
  const int n0 = blockIdx.y * 128;
  const int k0 = blockIdx.x * (KROW / NS);
  constexpr size_t krb = (size_t)KROW * 2;

  const int lrow8 = lane >> 3;
  const int swz = ((lane & 7) ^ lrow8) * 16;
  const char* gA = (const char*)amat;
  const char* gB = (const char*)bmat + (size_t)n0 * krb;

  f32x16 acc[2][2] = {};

  auto stage = [&](int buf, int c) {
    const size_t kb = (size_t)((k0 + c * 64) * 2) + swz;
    char* lb = lds + buf * 32768;
    #pragma unroll
    for (int j = 0; j < 4; ++j) {
      const int r = w * 32 + j * 8;
      gload16(gA + (size_t)(r + lrow8) * krb + kb, lb + r * 128);
      gload16(gB + (size_t)(r + lrow8) * krb + kb, lb + 16384 + r * 128);
    }
  };
  auto compute = [&](int buf) {
    const char* bA = lds + buf * 32768;
    const char* bB = bA + 16384;
    const int swr = (lane & 7) << 4;
    #pragma unroll
    for (int kk = 0; kk < 4; ++kk) {
      const int bc = (kk * 32 + (hi << 4)) ^ swr;
      half8 a0 = *(const half8*)(bA + (wm * 64 + l31) * 128 + bc);
      half8 a1 = *(const half8*)(bA + (wm * 64 + 32 + l31) * 128 + bc);
      half8 b0 = *(const half8*)(bB + (wn * 64 + l31) * 128 + bc);
      half8 b1 = *(const half8*)(bB + (wn * 64 + 32 + l31) * 128 + bc);
      acc[0][0] = mfma16(a0, b0, acc[0][0]);
      acc[0][1] = mfma16(a0, b1, acc[0][1]);
      acc[1][0] = mfma16(a1, b0, acc[1][0]);
      acc[1][1] = mfma16(a1, b1, acc[1][1]);
    }
  };

  stage(0, 0);
  stage(1, 1);
  pipe_bar8();
  #pragma unroll 1
  for (int c = 0; c < NCH - 2; ++c) {
    stage((c + 2) % 3, c + 2);
    compute(c % 3);
    pipe_bar8();
  }
  compute((NCH - 2) % 3);
  pipe_bar0();
  compute((NCH - 1) % 3);

  // C/D 32x32 frag: col = lane&31, row = (q&3)+8*(q>>2)+4*(lane>>5) [verified]
  f16* po = part + (size_t)blockIdx.x * (BSZ * NG);
  #pragma unroll
  for (int mf = 0; mf < 2; ++mf) {
    #pragma unroll
    for (int q = 0; q < 16; ++q) {
      const int row = wm * 64 + mf * 32 + (q & 3) + 8 * (q >> 2) + 4 * hi;
      #pragma unroll
      for (int nf = 0; nf < 2; ++nf) {
        const int col = n0 + wn * 64 + nf * 32 + l31;
        po[(size_t)row * NG + col] = (f16)acc[mf][nf][q];
      }
    }
  }
}

// sum NS fp16 partials (+ optional vin bias + relu) -> f16 (r12-verbatim)
template<int NS, int DOBIAS>
__global__ __launch_bounds__(256) void reduce_kernel(
    const f16* __restrict__ part, const float* __restrict__ v,
    const float* __restrict__ wih, f16* __restrict__ hout, int t)
{
  const int i = blockIdx.x * 256 + threadIdx.x;   // 131072 threads x 4 elems
  const int b = i >> 10;
  const int gi = (i & 1023) * 4;
  const half4v* p = (const half4v*)part + (((size_t)b * NG + gi) >> 2);
  float s[4];
  half4v q0 = p[0];
  #pragma unroll
  for (int j = 0; j < 4; ++j) s[j] = (float)q0[j];
  #pragma unroll
  for (int k = 1; k < NS; ++k) {
    half4v q = p[(size_t)k * (BSZ * NG / 4)];
    #pragma unroll
    for (int j = 0; j < 4; ++j) s[j] += (float)q[j];
  }
  half4v h;
  if (DOBIAS) {
    const float2 vb = *(const float2*)&v[((size_t)b * NT + t) * 2];
    const float4 wA = *(const float4*)(wih + (size_t)gi * 2);
    const float4 wB = *(const float4*)(wih + (size_t)gi * 2 + 4);
    h[0] = (f16)fmaxf(s[0] + vb.x * wA.x + vb.y * wA.y, 0.f);
    h[1] = (f16)fmaxf(s[1] + vb.x * wA.z + vb.y * wA.w, 0.f);
    h[2] = (f16)fmaxf(s[2] + vb.x * wB.x + vb.y * wB.y, 0.f);
    h[3] = (f16)fmaxf(s[3] + vb.x * wB.z + vb.y * wB.w, 0.f);
  } else {
    #pragma unroll
    for (int j = 0; j < 4; ++j) h[j] = (f16)s[j];
  }
  *(half4v*)&hout[(size_t)b * NG + gi] = h;
}

// ---------------- decode + fused log_softmax, counted-vmcnt 3-buf pipeline ----------------
// 128 chunks of K=32; LDS buf = A(64 rows x 64B) + B(512 rows x 64B) = 36KB x3.
// Swizzle: 16B unit u ^= (row>>1)&3 (== (l31>>1)&3 at read; 2-way max = free).
// Stage: per-lane swizzled GLOBAL src, lane-linear LDS dest (rule #21).
// Waits: vmcnt(4) steady (waves 0-3 have 5 loads/chunk, min(4) = safe over-wait).
__global__ __launch_bounds__(512, 1) void decode_kernel(
    const f16* __restrict__ hs, const f16* __restrict__ wdec16,
    float* __restrict__ out)
{
  constexpr int NCH = 128;
  __shared__ __align__(128) char lds[3 * 36864];
  __shared__ float redm[8][64];
  __shared__ float reds[8][64];
  __shared__ float gLS[64];
  const int tid = threadIdx.x;
  const int w = tid >> 6, lane = tid & 63;
  const int l31 = lane & 31, hi = lane >> 5;
  const int r0 = blockIdx.x * 64;

  const char* gA = (const char*)(hs + (size_t)r0 * NG);
  const char* gB = (const char*)wdec16;

  f32x16 acc[2][2] = {};

  auto stage = [&](int buf, int c) {
    char* lb = lds + buf * 36864;
    const size_t kb = (size_t)c * 64;   // byte offset along k (32 f16)
    if (w < 4) {                        // A: 4KB, waves 0-3, 1 wave-load each
      const int row = w * 16 + (lane >> 2);
      const int u = (lane & 3) ^ ((row >> 1) & 3);
      gload16(gA + (size_t)row * (NG * 2) + kb + u * 16, lb + w * 1024 + lane * 16);
    }
    #pragma unroll
    for (int j = 0; j < 4; ++j) {       // B: 32KB, 4 wave-loads per wave
      const int row = (w * 4 + j) * 16 + (lane >> 2);
      const int u = (lane & 3) ^ ((row >> 1) & 3);
      gload16(gB + (size_t)row * (NG * 2) + kb + u * 16,
              lb + 4096 + (w * 4 + j) * 1024 + lane * 16);
    }
  };
  auto compute = [&](int buf) {
    const char* bA = lds + buf * 36864;
    const char* bB = bA + 4096;
    const int sw = (l31 >> 1) & 3;      // swizzle value for all this lane's rows
    #pragma unroll
    for (int kk = 0; kk < 2; ++kk) {
      const int ub = ((kk * 2 + hi) ^ sw) * 16;
      half8 a0 = *(const half8*)(bA + l31 * 64 + ub);
      half8 a1 = *(const half8*)(bA + (l31 + 32) * 64 + ub);
      half8 b0 = *(const half8*)(bB + (w * 64 + l31) * 64 + ub);
      half8 b1 = *(const half8*)(bB + (w * 64 + 32 + l31) * 64 + ub);
      acc[0][0] = mfma16(a0, b0, acc[0][0]);
      acc[0][1] = mfma16(a0, b1, acc[0][1]);
      acc[1][0] = mfma16(a1, b0, acc[1][0]);
      acc[1][1] = mfma16(a1, b1, acc[1][1]);
    }
  };

  stage(0, 0);
  stage(1, 1);
  pipe_bar4();
  #pragma unroll 1
  for (int c = 0; c < NCH - 2; ++c) {
    stage((c + 2) % 3, c + 2);
    compute(c % 3);
    pipe_bar4();
  }
  compute((NCH - 2) % 3);
  pipe_bar0();
  compute((NCH - 1) % 3);

  #pragma unroll
  for (int mf = 0; mf < 2; ++mf) {
    #pragma unroll
    for (int q = 0; q < 16; ++q) {
      float m = fmaxf(acc[mf][0][q], acc[mf][1][q]);
      #pragma unroll
      for (int d = 1; d < 32; d <<= 1) m = fmaxf(m, __shfl_xor(m, d));
      if (l31 == q) redm[w][mf * 32 + (q & 3) + 8 * (q >> 2) + 4 * hi] = m;
    }
  }
  __syncthreads();
  if (tid < 64) {
    float M = redm[0][tid];
    #pragma unroll
    for (int ww = 1; ww < 8; ++ww) M = fmaxf(M, redm[ww][tid]);
    gLS[tid] = M;
  }
  __syncthreads();
  #pragma unroll
  for (int mf = 0; mf < 2; ++mf) {
    #pragma unroll
    for (int q = 0; q < 16; ++q) {
      const int rl = mf * 32 + (q & 3) + 8 * (q >> 2) + 4 * hi;
      const float M = gLS[rl];
      float e = __expf(acc[mf][0][q] - M) + __expf(acc[mf][1][q] - M);
      #pragma unroll
      for (int d = 1; d < 32; d <<= 1) e += __shfl_xor(e, d);
      if (l31 == q) reds[w][rl] = e;
    }
  }
  __syncthreads();
  if (tid < 64) {
    float S = reds[0][tid];
    #pragma unroll
    for (int ww = 1; ww < 8; ++ww) S += reds[ww][tid];
    gLS[tid] = gLS[tid] + __logf(S);
  }
  __syncthreads();
  #pragma unroll
  for (int mf = 0; mf < 2; ++mf) {
    #pragma unroll
    for (int q = 0; q < 16; ++q) {
      const int rl = mf * 32 + (q & 3) + 8 * (q >> 2) + 4 * hi;
      const int r = r0 + rl;
      const int tt = r >> 7, b = r & 127;
      const float lg = gLS[rl];
      float* orow = out + ((size_t)b * NT + tt) * NP + w * 64 + l31;
      orow[0]  = acc[mf][0][q] - lg;
      orow[32] = acc[mf][1][q] - lg;
    }
  }
}

// ---------------- host ----------------

extern "C" void kernel_launch(void* const* d_in, const int* in_sizes, int n_in,
                              void* d_out, int out_size, void* d_ws, size_t ws_size,
                              hipStream_t stream)
{
  const float* v    = (const float*)d_in[0];
  const float* p0   = (const float*)d_in[1];
  const float* wenc = (const float*)d_in[2];
  const float* wih  = (const float*)d_in[3];
  const float* whh  = (const float*)d_in[4];
  const float* wdec = (const float*)d_in[5];
  float* out = (float*)d_out;
  char* ws = (char*)d_ws;

  f16* whh16  = (f16*)(ws);                 // 33,554,432 B
  f16* wdec16 = (f16*)(ws + 33554432);      //  4,194,304 B
  f16* wenc16 = (f16*)(ws + 37748736);      //  4,194,304 B
  f16* p016   = (f16*)(ws + 41943040);      //    131,072 B
  f16* h016   = (f16*)(ws + 42074112);      //  1,048,576 B
  f16* hs     = (f16*)(ws + 43122688);      // 104,857,600 B
  f16* part   = (f16*)d_out;                // 8.4 MB f16 scratch until decode
  const size_t BNG = (size_t)BSZ * NG;

  conv_all<<<dim3(20544), dim3(256), 0, stream>>>(
      whh, wdec, wenc, p0, whh16, wdec16, wenc16, p016);

  // encode: h0 = p0 @ Wenc^T via K-split GEMM (K=512, 2 slices)
  gemm_ksplit<2, 512><<<dim3(2, 32), dim3(256), 0, stream>>>(wenc16, p016, part);
  reduce_kernel<2, 0><<<dim3(512), dim3(256), 0, stream>>>(part, v, wih, h016, 0);

  for (int t = 0; t < NT; ++t) {
    const f16* hp = (t == 0) ? h016 : hs + (size_t)(t - 1) * BNG;
    gemm_ksplit<8, 4096><<<dim3(8, 32), dim3(256), 0, stream>>>(whh16, hp, part);
    reduce_kernel<8, 1><<<dim3(512), dim3(256), 0, stream>>>(part, v, wih, hs + (size_t)t * BNG, t);
  }
  decode_kernel<<<dim3(200), dim3(512), 0, stream>>>(hs, wdec16, out);
}

// Round 16
// 1368.130 us; speedup vs baseline: 1.0053x; 1.0053x over previous
//
#include <hip/hip_runtime.h>

#define NG 4096
#define NP 512
#define BSZ 128
#define NT 100

typedef _Float16 f16;
typedef __attribute__((ext_vector_type(8))) _Float16 half8;
typedef __attribute__((ext_vector_type(4))) _Float16 half4v;
typedef __attribute__((ext_vector_type(16))) float f32x16;

__device__ inline f32x16 mfma16(half8 a, half8 b, f32x16 c) {
  return __builtin_amdgcn_mfma_f32_32x32x16_f16(a, b, c, 0, 0, 0);
}
__device__ __forceinline__ void gload16(const void* g, void* l) {
  __builtin_amdgcn_global_load_lds(
      (const __attribute__((address_space(1))) void*)g,
      (__attribute__((address_space(3))) void*)l, 16, 0, 0);
}
__device__ __forceinline__ void pipe_bar8() {
  __builtin_amdgcn_sched_barrier(0);
  asm volatile("s_waitcnt vmcnt(8)" ::: "memory");
  __builtin_amdgcn_s_barrier();
  __builtin_amdgcn_sched_barrier(0);
}
__device__ __forceinline__ void pipe_bar0() {
  __builtin_amdgcn_sched_barrier(0);
  asm volatile("s_waitcnt vmcnt(0)" ::: "memory");
  __builtin_amdgcn_s_barrier();
  __builtin_amdgcn_sched_barrier(0);
}
// decode: chunk = 9 loads/wave -> after issuing stage(c+1), vmcnt(9) == chunk c landed
__device__ __forceinline__ void pipe_bar9() {
  __builtin_amdgcn_sched_barrier(0);
  asm volatile("s_waitcnt vmcnt(9)" ::: "memory");
  __builtin_amdgcn_s_barrier();
  __builtin_amdgcn_sched_barrier(0);
}
// buffer-reuse barrier: only needs this wave's ds_reads retired (lgkm), NOT vmcnt
__device__ __forceinline__ void pipe_bar_lgkm() {
  __builtin_amdgcn_sched_barrier(0);
  asm volatile("s_waitcnt lgkmcnt(0)" ::: "memory");
  __builtin_amdgcn_s_barrier();
  __builtin_amdgcn_sched_barrier(0);
}

// ---------------- prep: all f32 -> fp16 conversions in ONE launch ----------------
__global__ __launch_bounds__(256) void conv_all(
    const float* __restrict__ whh, const float* __restrict__ wdec,
    const float* __restrict__ wenc, const float* __restrict__ p0,
    f16* __restrict__ whh16, f16* __restrict__ wdec16,
    f16* __restrict__ wenc16, f16* __restrict__ p016)
{
  int i = blockIdx.x * 256 + threadIdx.x;
  const float* src; f16* dst; int off;
  if (i < 4194304)      { src = whh;  dst = whh16;  off = 0; }
  else if (i < 4718592) { src = wdec; dst = wdec16; off = 4194304; }
  else if (i < 5242880) { src = wenc; dst = wenc16; off = 4718592; }
  else if (i < 5259264) { src = p0;   dst = p016;   off = 5242880; }
  else return;
  const int j = i - off;
  const float4 x = ((const float4*)src)[j];
  half4v h = { (f16)x.x, (f16)x.y, (f16)x.z, (f16)x.w };
  *(half4v*)&dst[(size_t)j * 4] = h;
}

// ---------------- K-split fp16 GEMM, 3-buf counted-vmcnt pipeline (r12-verbatim) ----------------
template<int NS, int KROW>
__global__ __launch_bounds__(256, 1) void gemm_ksplit(
    const f16* __restrict__ bmat, const f16* __restrict__ amat,
    f16* __restrict__ part)
{
  constexpr int NCH = KROW / (NS * 64);
  __shared__ __align__(128) char lds[3 * 32768];
  const int tid = threadIdx.x;
  const int w = tid >> 6, lane = tid & 63;
  const int wm = w & 1, wn = w >> 1;
  const int l31 = lane & 31, hi = lane >> 5;
  const int n0 = blockIdx.y * 128;
  const int k0 = blockIdx.x * (KROW / NS);
  constexpr size_t krb = (size_t)KROW * 2;

  const int lrow8 = lane >> 3;
  const int swz = ((lane & 7) ^ lrow8) * 16;
  const char* gA = (const char*)amat;
  const char* gB = (const char*)bmat + (size_t)n0 * krb;

  f32x16 acc[2][2] = {};

  auto stage = [&](int buf, int c) {
    const size_t kb = (size_t)((k0 + c * 64) * 2) + swz;
    char* lb = lds + buf * 32768;
    #pragma unroll
    for (int j = 0; j < 4; ++j) {
      const int r = w * 32 + j * 8;
      gload16(gA + (size_t)(r + lrow8) * krb + kb, lb + r * 128);
      gload16(gB + (size_t)(r + lrow8) * krb + kb, lb + 16384 + r * 128);
    }
  };
  auto compute = [&](int buf) {
    const char* bA = lds + buf * 32768;
    const char* bB = bA + 16384;
    const int swr = (lane & 7) << 4;
    #pragma unroll
    for (int kk = 0; kk < 4; ++kk) {
      const int bc = (kk * 32 + (hi << 4)) ^ swr;
      half8 a0 = *(const half8*)(bA + (wm * 64 + l31) * 128 + bc);
      half8 a1 = *(const half8*)(bA + (wm * 64 + 32 + l31) * 128 + bc);
      half8 b0 = *(const half8*)(bB + (wn * 64 + l31) * 128 + bc);
      half8 b1 = *(const half8*)(bB + (wn * 64 + 32 + l31) * 128 + bc);
      acc[0][0] = mfma16(a0, b0, acc[0][0]);
      acc[0][1] = mfma16(a0, b1, acc[0][1]);
      acc[1][0] = mfma16(a1, b0, acc[1][0]);
      acc[1][1] = mfma16(a1, b1, acc[1][1]);
    }
  };

  stage(0, 0);
  stage(1, 1);
  pipe_bar8();
  #pragma unroll 1
  for (int c = 0; c < NCH - 2; ++c) {
    stage((c + 2) % 3, c + 2);
    compute(c % 3);
    pipe_bar8();
  }
  compute((NCH - 2) % 3);
  pipe_bar0();
  compute((NCH - 1) % 3);

  // C/D 32x32 frag: col = lane&31, row = (q&3)+8*(q>>2)+4*(lane>>5) [verified]
  f16* po = part + (size_t)blockIdx.x * (BSZ * NG);
  #pragma unroll
  for (int mf = 0; mf < 2; ++mf) {
    #pragma unroll
    for (int q = 0; q < 16; ++q) {
      const int row = wm * 64 + mf * 32 + (q & 3) + 8 * (q >> 2) + 4 * hi;
      #pragma unroll
      for (int nf = 0; nf < 2; ++nf) {
        const int col = n0 + wn * 64 + nf * 32 + l31;
        po[(size_t)row * NG + col] = (f16)acc[mf][nf][q];
      }
    }
  }
}

// sum NS fp16 partials (+ optional vin bias + relu) -> f16 (r12-verbatim)
template<int NS, int DOBIAS>
__global__ __launch_bounds__(256) void reduce_kernel(
    const f16* __restrict__ part, const float* __restrict__ v,
    const float* __restrict__ wih, f16* __restrict__ hout, int t)
{
  const int i = blockIdx.x * 256 + threadIdx.x;   // 131072 threads x 4 elems
  const int b = i >> 10;
  const int gi = (i & 1023) * 4;
  const half4v* p = (const half4v*)part + (((size_t)b * NG + gi) >> 2);
  float s[4];
  half4v q0 = p[0];
  #pragma unroll
  for (int j = 0; j < 4; ++j) s[j] = (float)q0[j];
  #pragma unroll
  for (int k = 1; k < NS; ++k) {
    half4v q = p[(size_t)k * (BSZ * NG / 4)];
    #pragma unroll
    for (int j = 0; j < 4; ++j) s[j] += (float)q[j];
  }
  half4v h;
  if (DOBIAS) {
    const float2 vb = *(const float2*)&v[((size_t)b * NT + t) * 2];
    const float4 wA = *(const float4*)(wih + (size_t)gi * 2);
    const float4 wB = *(const float4*)(wih + (size_t)gi * 2 + 4);
    h[0] = (f16)fmaxf(s[0] + vb.x * wA.x + vb.y * wA.y, 0.f);
    h[1] = (f16)fmaxf(s[1] + vb.x * wA.z + vb.y * wA.w, 0.f);
    h[2] = (f16)fmaxf(s[2] + vb.x * wB.x + vb.y * wB.y, 0.f);
    h[3] = (f16)fmaxf(s[3] + vb.x * wB.z + vb.y * wB.w, 0.f);
  } else {
    #pragma unroll
    for (int j = 0; j < 4; ++j) h[j] = (f16)s[j];
  }
  *(half4v*)&hout[(size_t)b * NG + gi] = h;
}

// ---------------- decode + fused log_softmax ----------------
// r4 decode byte-identical addresses/LDS; ONLY the waits changed:
// per chunk 9 loads/wave -> vmcnt(9) after issuing stage(c+1) == chunk c landed
// (chunk c+1 stays in flight through compute(c)); buffer-reuse barrier waits
// lgkmcnt(0) only. Full vmcnt(0) drain only before the last compute.
__global__ __launch_bounds__(512, 2) void decode_kernel(
    const f16* __restrict__ hs, const f16* __restrict__ wdec16,
    float* __restrict__ out)
{
  __shared__ __align__(128) char lds[2 * 73728];
  __shared__ float redm[8][64];
  __shared__ float reds[8][64];
  __shared__ float gLS[64];
  const int tid = threadIdx.x;
  const int w = tid >> 6, lane = tid & 63;
  const int l31 = lane & 31, hi = lane >> 5;
  const int r0 = blockIdx.x * 64;

  const int lrow8 = lane >> 3;
  const int swz = ((lane & 7) ^ lrow8) * 16;
  const char* gA = (const char*)(hs + (size_t)r0 * NG);
  const char* gB = (const char*)wdec16;

  f32x16 acc[2][2] = {};

  auto stage = [&](int buf, int c) {
    const size_t kb = (size_t)(c * 128) + swz;
    char* lb = lds + buf * 73728;
    gload16(gA + (size_t)(w * 8 + lrow8) * (NG * 2) + kb, lb + w * 1024);
    #pragma unroll
    for (int j = 0; j < 8; ++j) {
      const int r = w * 64 + j * 8;
      gload16(gB + (size_t)(r + lrow8) * (NG * 2) + kb, lb + 8192 + r * 128);
    }
  };
  auto compute = [&](int buf) {
    const char* bA = lds + buf * 73728;
    const char* bB = bA + 8192;
    const int swr = (lane & 7) << 4;
    #pragma unroll
    for (int kk = 0; kk < 4; ++kk) {
      const int bc = (kk * 32 + (hi << 4)) ^ swr;
      half8 a0 = *(const half8*)(bA + l31 * 128 + bc);
      half8 a1 = *(const half8*)(bA + (32 + l31) * 128 + bc);
      half8 b0 = *(const half8*)(bB + (w * 64 + l31) * 128 + bc);
      half8 b1 = *(const half8*)(bB + (w * 64 + 32 + l31) * 128 + bc);
      acc[0][0] = mfma16(a0, b0, acc[0][0]);
      acc[0][1] = mfma16(a0, b1, acc[0][1]);
      acc[1][0] = mfma16(a1, b0, acc[1][0]);
      acc[1][1] = mfma16(a1, b1, acc[1][1]);
    }
  };

  stage(0, 0);
  #pragma unroll 1
  for (int c = 0; c < 63; ++c) {
    stage((c + 1) & 1, c + 1);   // chunk c+1 in flight through compute(c)
    pipe_bar9();                 // chunk c landed (9 newer outstanding allowed)
    compute(c & 1);
    pipe_bar_lgkm();             // reads of buf (c&1) retired; safe to overwrite
  }
  pipe_bar0();                   // chunk 63 landed
  compute(63 & 1);

  #pragma unroll
  for (int mf = 0; mf < 2; ++mf) {
    #pragma unroll
    for (int q = 0; q < 16; ++q) {
      float m = fmaxf(acc[mf][0][q], acc[mf][1][q]);
      #pragma unroll
      for (int d = 1; d < 32; d <<= 1) m = fmaxf(m, __shfl_xor(m, d));
      if (l31 == q) redm[w][mf * 32 + (q & 3) + 8 * (q >> 2) + 4 * hi] = m;
    }
  }
  __syncthreads();
  if (tid < 64) {
    float M = redm[0][tid];
    #pragma unroll
    for (int ww = 1; ww < 8; ++ww) M = fmaxf(M, redm[ww][tid]);
    gLS[tid] = M;
  }
  __syncthreads();
  #pragma unroll
  for (int mf = 0; mf < 2; ++mf) {
    #pragma unroll
    for (int q = 0; q < 16; ++q) {
      const int rl = mf * 32 + (q & 3) + 8 * (q >> 2) + 4 * hi;
      const float M = gLS[rl];
      float e = __expf(acc[mf][0][q] - M) + __expf(acc[mf][1][q] - M);
      #pragma unroll
      for (int d = 1; d < 32; d <<= 1) e += __shfl_xor(e, d);
      if (l31 == q) reds[w][rl] = e;
    }
  }
  __syncthreads();
  if (tid < 64) {
    float S = reds[0][tid];
    #pragma unroll
    for (int ww = 1; ww < 8; ++ww) S += reds[ww][tid];
    gLS[tid] = gLS[tid] + __logf(S);
  }
  __syncthreads();
  #pragma unroll
  for (int mf = 0; mf < 2; ++mf) {
    #pragma unroll
    for (int q = 0; q < 16; ++q) {
      const int rl = mf * 32 + (q & 3) + 8 * (q >> 2) + 4 * hi;
      const int r = r0 + rl;
      const int tt = r >> 7, b = r & 127;
      const float lg = gLS[rl];
      float* orow = out + ((size_t)b * NT + tt) * NP + w * 64 + l31;
      orow[0]  = acc[mf][0][q] - lg;
      orow[32] = acc[mf][1][q] - lg;
    }
  }
}

// ---------------- host ----------------

extern "C" void kernel_launch(void* const* d_in, const int* in_sizes, int n_in,
                              void* d_out, int out_size, void* d_ws, size_t ws_size,
                              hipStream_t stream)
{
  const float* v    = (const float*)d_in[0];
  const float* p0   = (const float*)d_in[1];
  const float* wenc = (const float*)d_in[2];
  const float* wih  = (const float*)d_in[3];
  const float* whh  = (const float*)d_in[4];
  const float* wdec = (const float*)d_in[5];
  float* out = (float*)d_out;
  char* ws = (char*)d_ws;

  f16* whh16  = (f16*)(ws);                 // 33,554,432 B
  f16* wdec16 = (f16*)(ws + 33554432);      //  4,194,304 B
  f16* wenc16 = (f16*)(ws + 37748736);      //  4,194,304 B
  f16* p016   = (f16*)(ws + 41943040);      //    131,072 B
  f16* h016   = (f16*)(ws + 42074112);      //  1,048,576 B
  f16* hs     = (f16*)(ws + 43122688);      // 104,857,600 B
  f16* part   = (f16*)d_out;                // 8.4 MB f16 scratch until decode
  const size_t BNG = (size_t)BSZ * NG;

  conv_all<<<dim3(20544), dim3(256), 0, stream>>>(
      whh, wdec, wenc, p0, whh16, wdec16, wenc16, p016);

  // encode: h0 = p0 @ Wenc^T via K-split GEMM (K=512, 2 slices)
  gemm_ksplit<2, 512><<<dim3(2, 32), dim3(256), 0, stream>>>(wenc16, p016, part);
  reduce_kernel<2, 0><<<dim3(512), dim3(256), 0, stream>>>(part, v, wih, h016, 0);

  for (int t = 0; t < NT; ++t) {
    const f16* hp = (t == 0) ? h016 : hs + (size_t)(t - 1) * BNG;
    gemm_ksplit<8, 4096><<<dim3(8, 32), dim3(256), 0, stream>>>(whh16, hp, part);
    reduce_kernel<8, 1><<<dim3(512), dim3(256), 0, stream>>>(part, v, wih, hs + (size_t)t * BNG, t);
  }
  decode_kernel<<<dim3(200), dim3(512), 0, stream>>>(hs, wdec16, out);
}

// Round 17
// 1349.915 us; speedup vs baseline: 1.0189x; 1.0135x over previous
//
#include <hip/hip_runtime.h>

#define NG 4096
#define NP 512
#define BSZ 128
#define NT 100

typedef _Float16 f16;
typedef __attribute__((ext_vector_type(8))) _Float16 half8;
typedef __attribute__((ext_vector_type(4))) _Float16 half4v;
typedef __attribute__((ext_vector_type(16))) float f32x16;

__device__ inline f32x16 mfma16(half8 a, half8 b, f32x16 c) {
  return __builtin_amdgcn_mfma_f32_32x32x16_f16(a, b, c, 0, 0, 0);
}
__device__ __forceinline__ void gload16(const void* g, void* l) {
  __builtin_amdgcn_global_load_lds(
      (const __attribute__((address_space(1))) void*)g,
      (__attribute__((address_space(3))) void*)l, 16, 0, 0);
}
__device__ __forceinline__ void pipe_bar8() {
  __builtin_amdgcn_sched_barrier(0);
  asm volatile("s_waitcnt vmcnt(8)" ::: "memory");
  __builtin_amdgcn_s_barrier();
  __builtin_amdgcn_sched_barrier(0);
}
__device__ __forceinline__ void pipe_bar0() {
  __builtin_amdgcn_sched_barrier(0);
  asm volatile("s_waitcnt vmcnt(0)" ::: "memory");
  __builtin_amdgcn_s_barrier();
  __builtin_amdgcn_sched_barrier(0);
}

// ---------------- prep: all f32 -> fp16 conversions in ONE launch ----------------
__global__ __launch_bounds__(256) void conv_all(
    const float* __restrict__ whh, const float* __restrict__ wdec,
    const float* __restrict__ wenc, const float* __restrict__ p0,
    f16* __restrict__ whh16, f16* __restrict__ wdec16,
    f16* __restrict__ wenc16, f16* __restrict__ p016)
{
  int i = blockIdx.x * 256 + threadIdx.x;
  const float* src; f16* dst; int off;
  if (i < 4194304)      { src = whh;  dst = whh16;  off = 0; }
  else if (i < 4718592) { src = wdec; dst = wdec16; off = 4194304; }
  else if (i < 5242880) { src = wenc; dst = wenc16; off = 4718592; }
  else if (i < 5259264) { src = p0;   dst = p016;   off = 5242880; }
  else return;
  const int j = i - off;
  const float4 x = ((const float4*)src)[j];
  half4v h = { (f16)x.x, (f16)x.y, (f16)x.z, (f16)x.w };
  *(half4v*)&dst[(size_t)j * 4] = h;
}

// ---------------- K-split fp16 GEMM, 3-buf counted-vmcnt pipeline (r12-verbatim) ----------------
// part[bx][m][n] = sum_{k in slice bx} A[m][k] * B[n][k]
// KS=8: grid (8,32), 256 thr = 4 waves (2M x 2N), wave tile 64x64, NCH=8.
// id%8 XCD round-robin pins one 4MB B k-slice per XCD across all steps (L2-res).
// LDS: 3 x (A 16K + B 16K); XOR swizzle on GLOBAL source (rule #21), read same
// XOR. Pipeline: stage(c+2) -> compute(c) -> vmcnt(8) + raw s_barrier (T4).
template<int NS, int KROW>
__global__ __launch_bounds__(256, 1) void gemm_ksplit(
    const f16* __restrict__ bmat, const f16* __restrict__ amat,
    f16* __restrict__ part)
{
  constexpr int NCH = KROW / (NS * 64);   // 64-K chunks per block (8 step, 4 enc)
  __shared__ __align__(128) char lds[3 * 32768];
  const int tid = threadIdx.x;
  const int w = tid >> 6, lane = tid & 63;
  const int wm = w & 1, wn = w >> 1;
  const int l31 = lane & 31, hi = lane >> 5;
  const int n0 = blockIdx.y * 128;
  const int k0 = blockIdx.x * (KROW / NS);
  constexpr size_t krb = (size_t)KROW * 2;

  const int lrow8 = lane >> 3;
  const int swz = ((lane & 7) ^ lrow8) * 16;
  const char* gA = (const char*)amat;
  const char* gB = (const char*)bmat + (size_t)n0 * krb;

  f32x16 acc[2][2] = {};

  auto stage = [&](int buf, int c) {
    const size_t kb = (size_t)((k0 + c * 64) * 2) + swz;
    char* lb = lds + buf * 32768;
    #pragma unroll
    for (int j = 0; j < 4; ++j) {
      const int r = w * 32 + j * 8;
      gload16(gA + (size_t)(r + lrow8) * krb + kb, lb + r * 128);
      gload16(gB + (size_t)(r + lrow8) * krb + kb, lb + 16384 + r * 128);
    }
  };
  auto compute = [&](int buf) {
    const char* bA = lds + buf * 32768;
    const char* bB = bA + 16384;
    const int swr = (lane & 7) << 4;
    #pragma unroll
    for (int kk = 0; kk < 4; ++kk) {
      const int bc = (kk * 32 + (hi << 4)) ^ swr;
      half8 a0 = *(const half8*)(bA + (wm * 64 + l31) * 128 + bc);
      half8 a1 = *(const half8*)(bA + (wm * 64 + 32 + l31) * 128 + bc);
      half8 b0 = *(const half8*)(bB + (wn * 64 + l31) * 128 + bc);
      half8 b1 = *(const half8*)(bB + (wn * 64 + 32 + l31) * 128 + bc);
      acc[0][0] = mfma16(a0, b0, acc[0][0]);
      acc[0][1] = mfma16(a0, b1, acc[0][1]);
      acc[1][0] = mfma16(a1, b0, acc[1][0]);
      acc[1][1] = mfma16(a1, b1, acc[1][1]);
    }
  };

  // prologue: 2-deep prefetch
  stage(0, 0);
  stage(1, 1);
  pipe_bar8();                     // chunk0 landed (8 of chunk1 may fly)
  #pragma unroll 1
  for (int c = 0; c < NCH - 2; ++c) {
    stage((c + 2) % 3, c + 2);     // keep 2 chunks in flight
    compute(c % 3);
    pipe_bar8();                   // chunk c+1 landed; c+2 still flying
  }
  compute((NCH - 2) % 3);
  pipe_bar0();                     // last chunk landed
  compute((NCH - 1) % 3);

  // C/D 32x32 frag: col = lane&31, row = (q&3)+8*(q>>2)+4*(lane>>5) [verified]
  f16* po = part + (size_t)blockIdx.x * (BSZ * NG);
  #pragma unroll
  for (int mf = 0; mf < 2; ++mf) {
    #pragma unroll
    for (int q = 0; q < 16; ++q) {
      const int row = wm * 64 + mf * 32 + (q & 3) + 8 * (q >> 2) + 4 * hi;
      #pragma unroll
      for (int nf = 0; nf < 2; ++nf) {
        const int col = n0 + wn * 64 + nf * 32 + l31;
        po[(size_t)row * NG + col] = (f16)acc[mf][nf][q];
      }
    }
  }
}

// sum NS fp16 partials (+ optional vin bias + relu) -> f16 (r12-verbatim)
// 512 blocks x 256 thr, 4 elems/thread.
template<int NS, int DOBIAS>
__global__ __launch_bounds__(256) void reduce_kernel(
    const f16* __restrict__ part, const float* __restrict__ v,
    const float* __restrict__ wih, f16* __restrict__ hout, int t)
{
  const int i = blockIdx.x * 256 + threadIdx.x;   // 131072 threads x 4 elems
  const int b = i >> 10;
  const int gi = (i & 1023) * 4;
  const half4v* p = (const half4v*)part + (((size_t)b * NG + gi) >> 2);
  float s[4];
  half4v q0 = p[0];
  #pragma unroll
  for (int j = 0; j < 4; ++j) s[j] = (float)q0[j];
  #pragma unroll
  for (int k = 1; k < NS; ++k) {
    half4v q = p[(size_t)k * (BSZ * NG / 4)];
    #pragma unroll
    for (int j = 0; j < 4; ++j) s[j] += (float)q[j];
  }
  half4v h;
  if (DOBIAS) {
    const float2 vb = *(const float2*)&v[((size_t)b * NT + t) * 2];
    const float4 wA = *(const float4*)(wih + (size_t)gi * 2);
    const float4 wB = *(const float4*)(wih + (size_t)gi * 2 + 4);
    h[0] = (f16)fmaxf(s[0] + vb.x * wA.x + vb.y * wA.y, 0.f);
    h[1] = (f16)fmaxf(s[1] + vb.x * wA.z + vb.y * wA.w, 0.f);
    h[2] = (f16)fmaxf(s[2] + vb.x * wB.x + vb.y * wB.y, 0.f);
    h[3] = (f16)fmaxf(s[3] + vb.x * wB.z + vb.y * wB.w, 0.f);
  } else {
    #pragma unroll
    for (int j = 0; j < 4; ++j) h[j] = (f16)s[j];
  }
  *(half4v*)&hout[(size_t)b * NG + gi] = h;
}

// ---------------- decode + fused log_softmax (r4 version, 114 us measured) ----------------
__global__ __launch_bounds__(512, 2) void decode_kernel(
    const f16* __restrict__ hs, const f16* __restrict__ wdec16,
    float* __restrict__ out)
{
  __shared__ __align__(128) char lds[2 * 73728];
  __shared__ float redm[8][64];
  __shared__ float reds[8][64];
  __shared__ float gLS[64];
  const int tid = threadIdx.x;
  const int w = tid >> 6, lane = tid & 63;
  const int l31 = lane & 31, hi = lane >> 5;
  const int r0 = blockIdx.x * 64;

  const int lrow8 = lane >> 3;
  const int swz = ((lane & 7) ^ lrow8) * 16;
  const char* gA = (const char*)(hs + (size_t)r0 * NG);
  const char* gB = (const char*)wdec16;

  f32x16 acc[2][2] = {};

  auto stage = [&](int buf, int c) {
    const size_t kb = (size_t)(c * 128) + swz;
    char* lb = lds + buf * 73728;
    gload16(gA + (size_t)(w * 8 + lrow8) * (NG * 2) + kb, lb + w * 1024);
    #pragma unroll
    for (int j = 0; j < 8; ++j) {
      const int r = w * 64 + j * 8;
      gload16(gB + (size_t)(r + lrow8) * (NG * 2) + kb, lb + 8192 + r * 128);
    }
  };
  auto compute = [&](int buf) {
    const char* bA = lds + buf * 73728;
    const char* bB = bA + 8192;
    const int swr = (lane & 7) << 4;
    #pragma unroll
    for (int kk = 0; kk < 4; ++kk) {
      const int bc = (kk * 32 + (hi << 4)) ^ swr;
      half8 a0 = *(const half8*)(bA + l31 * 128 + bc);
      half8 a1 = *(const half8*)(bA + (32 + l31) * 128 + bc);
      half8 b0 = *(const half8*)(bB + (w * 64 + l31) * 128 + bc);
      half8 b1 = *(const half8*)(bB + (w * 64 + 32 + l31) * 128 + bc);
      acc[0][0] = mfma16(a0, b0, acc[0][0]);
      acc[0][1] = mfma16(a0, b1, acc[0][1]);
      acc[1][0] = mfma16(a1, b0, acc[1][0]);
      acc[1][1] = mfma16(a1, b1, acc[1][1]);
    }
  };

  stage(0, 0);
  __syncthreads();
  #pragma unroll 1
  for (int c = 0; c < 64; ++c) {
    if (c < 63) stage((c + 1) & 1, c + 1);
    compute(c & 1);
    __syncthreads();
  }

  #pragma unroll
  for (int mf = 0; mf < 2; ++mf) {
    #pragma unroll
    for (int q = 0; q < 16; ++q) {
      float m = fmaxf(acc[mf][0][q], acc[mf][1][q]);
      #pragma unroll
      for (int d = 1; d < 32; d <<= 1) m = fmaxf(m, __shfl_xor(m, d));
      if (l31 == q) redm[w][mf * 32 + (q & 3) + 8 * (q >> 2) + 4 * hi] = m;
    }
  }
  __syncthreads();
  if (tid < 64) {
    float M = redm[0][tid];
    #pragma unroll
    for (int ww = 1; ww < 8; ++ww) M = fmaxf(M, redm[ww][tid]);
    gLS[tid] = M;
  }
  __syncthreads();
  #pragma unroll
  for (int mf = 0; mf < 2; ++mf) {
    #pragma unroll
    for (int q = 0; q < 16; ++q) {
      const int rl = mf * 32 + (q & 3) + 8 * (q >> 2) + 4 * hi;
      const float M = gLS[rl];
      float e = __expf(acc[mf][0][q] - M) + __expf(acc[mf][1][q] - M);
      #pragma unroll
      for (int d = 1; d < 32; d <<= 1) e += __shfl_xor(e, d);
      if (l31 == q) reds[w][rl] = e;
    }
  }
  __syncthreads();
  if (tid < 64) {
    float S = reds[0][tid];
    #pragma unroll
    for (int ww = 1; ww < 8; ++ww) S += reds[ww][tid];
    gLS[tid] = gLS[tid] + __logf(S);
  }
  __syncthreads();
  #pragma unroll
  for (int mf = 0; mf < 2; ++mf) {
    #pragma unroll
    for (int q = 0; q < 16; ++q) {
      const int rl = mf * 32 + (q & 3) + 8 * (q >> 2) + 4 * hi;
      const int r = r0 + rl;
      const int tt = r >> 7, b = r & 127;
      const float lg = gLS[rl];
      float* orow = out + ((size_t)b * NT + tt) * NP + w * 64 + l31;
      orow[0]  = acc[mf][0][q] - lg;
      orow[32] = acc[mf][1][q] - lg;
    }
  }
}

// ---------------- host ----------------

extern "C" void kernel_launch(void* const* d_in, const int* in_sizes, int n_in,
                              void* d_out, int out_size, void* d_ws, size_t ws_size,
                              hipStream_t stream)
{
  const float* v    = (const float*)d_in[0];
  const float* p0   = (const float*)d_in[1];
  const float* wenc = (const float*)d_in[2];
  const float* wih  = (const float*)d_in[3];
  const float* whh  = (const float*)d_in[4];
  const float* wdec = (const float*)d_in[5];
  float* out = (float*)d_out;
  char* ws = (char*)d_ws;

  f16* whh16  = (f16*)(ws);                 // 33,554,432 B
  f16* wdec16 = (f16*)(ws + 33554432);      //  4,194,304 B
  f16* wenc16 = (f16*)(ws + 37748736);      //  4,194,304 B
  f16* p016   = (f16*)(ws + 41943040);      //    131,072 B
  f16* h016   = (f16*)(ws + 42074112);      //  1,048,576 B
  f16* hs     = (f16*)(ws + 43122688);      // 104,857,600 B
  f16* part   = (f16*)d_out;                // 8.4 MB f16 scratch until decode
  const size_t BNG = (size_t)BSZ * NG;

  conv_all<<<dim3(20544), dim3(256), 0, stream>>>(
      whh, wdec, wenc, p0, whh16, wdec16, wenc16, p016);

  // encode: h0 = p0 @ Wenc^T via K-split GEMM (K=512, 2 slices)
  gemm_ksplit<2, 512><<<dim3(2, 32), dim3(256), 0, stream>>>(wenc16, p016, part);
  reduce_kernel<2, 0><<<dim3(512), dim3(256), 0, stream>>>(part, v, wih, h016, 0);

  for (int t = 0; t < NT; ++t) {
    const f16* hp = (t == 0) ? h016 : hs + (size_t)(t - 1) * BNG;
    gemm_ksplit<8, 4096><<<dim3(8, 32), dim3(256), 0, stream>>>(whh16, hp, part);
    reduce_kernel<8, 1><<<dim3(512), dim3(256), 0, stream>>>(part, v, wih, hs + (size_t)t * BNG, t);
  }
  decode_kernel<<<dim3(200), dim3(512), 0, stream>>>(hs, wdec16, out);
}